// Round 8
// baseline (435.121 us; speedup 1.0000x reference)
//
#include <hip/hip_runtime.h>
#include <math.h>

#define BQ 65536
#define NC 512
#define DD 512
#define BM 64
#define BN 256
#define BK 32
#define MARGIN 3e-3f
#define FINF 3.402823466e38f

// A-tile LDS rows padded to 40 shorts (80 B): frag ds_read_b128 lands on
// banks (c*20+g*4)%32 -> 2-way max (free per m136).
#define ASTR 40

typedef short bf16x8 __attribute__((ext_vector_type(8)));
typedef float f32x4 __attribute__((ext_vector_type(4)));

__device__ __forceinline__ unsigned int cvt_pk_bf16(float a, float b) {
    unsigned int r;
    asm("v_cvt_pk_bf16_f32 %0, %1, %2" : "=v"(r) : "v"(a), "v"(b));
    return r;  // low16 = bf16(a) RNE, high16 = bf16(b)
}

// Split 4 fp32 into packed bf16 hi-pairs and lo-pairs (verified since r3).
__device__ __forceinline__ void split4(float4 v, uint2* hi, uint2* lo) {
    unsigned int h0 = cvt_pk_bf16(v.x, v.y);
    unsigned int h1 = cvt_pk_bf16(v.z, v.w);
    float hx = __uint_as_float(h0 << 16);
    float hy = __uint_as_float(h0 & 0xFFFF0000u);
    float hz = __uint_as_float(h1 << 16);
    float hw = __uint_as_float(h1 & 0xFFFF0000u);
    *hi = make_uint2(h0, h1);
    *lo = make_uint2(cvt_pk_bf16(v.x - hx, v.y - hy),
                     cvt_pk_bf16(v.z - hz, v.w - hw));
}

// 8 fp32 -> bf16 hi + lo vectors (same arithmetic as split4).
__device__ __forceinline__ void cvt8(float4 f0, float4 f1,
                                     bf16x8* hi, bf16x8* lo) {
    unsigned int h01 = cvt_pk_bf16(f0.x, f0.y);
    unsigned int h23 = cvt_pk_bf16(f0.z, f0.w);
    unsigned int h45 = cvt_pk_bf16(f1.x, f1.y);
    unsigned int h67 = cvt_pk_bf16(f1.z, f1.w);
    float a0 = __uint_as_float(h01 << 16), a1 = __uint_as_float(h01 & 0xFFFF0000u);
    float a2 = __uint_as_float(h23 << 16), a3 = __uint_as_float(h23 & 0xFFFF0000u);
    float a4 = __uint_as_float(h45 << 16), a5 = __uint_as_float(h45 & 0xFFFF0000u);
    float a6 = __uint_as_float(h67 << 16), a7 = __uint_as_float(h67 & 0xFFFF0000u);
    union { bf16x8 v; unsigned int u[4]; } H, L;
    H.u[0] = h01; H.u[1] = h23; H.u[2] = h45; H.u[3] = h67;
    L.u[0] = cvt_pk_bf16(f0.x - a0, f0.y - a1);
    L.u[1] = cvt_pk_bf16(f0.z - a2, f0.w - a3);
    L.u[2] = cvt_pk_bf16(f1.x - a4, f1.y - a5);
    L.u[3] = cvt_pk_bf16(f1.z - a6, f1.w - a7);
    *hi = H.v; *lo = L.v;
}

__device__ __forceinline__ float pw128_sq(const float* __restrict__ p) {
    float r[8];
    #pragma unroll
    for (int j = 0; j < 8; ++j) r[j] = 0.0f;
    #pragma unroll
    for (int q = 0; q < 32; ++q) {
        float4 v = *(const float4*)(p + q * 4);
        const int e = (q & 1) << 2;
        r[e + 0] = __fadd_rn(r[e + 0], __fmul_rn(v.x, v.x));
        r[e + 1] = __fadd_rn(r[e + 1], __fmul_rn(v.y, v.y));
        r[e + 2] = __fadd_rn(r[e + 2], __fmul_rn(v.z, v.z));
        r[e + 3] = __fadd_rn(r[e + 3], __fmul_rn(v.w, v.w));
    }
    return __fadd_rn(__fadd_rn(__fadd_rn(r[0], r[1]), __fadd_rn(r[2], r[3])),
                     __fadd_rn(__fadd_rn(r[4], r[5]), __fadd_rn(r[6], r[7])));
}

// Pass 1: BM=64, 4 waves x (64x64) tiles. A double-buffered in LDS as split
// bf16 (ONE barrier/step); B global->reg ring (static indices). Metric
// m = csq - 2 z.c, best+second-best; marginal rows -> fp64 fixup worklist.
__global__ __launch_bounds__(256, 4) void codebook_kernel(
    const float* __restrict__ Z, const float* __restrict__ Cb,
    float* __restrict__ out, int* __restrict__ wslist, int cap) {

    __shared__ __align__(16) unsigned short Ahi[2][BM * ASTR];
    __shared__ __align__(16) unsigned short Alo[2][BM * ASTR];
    __shared__ float csq[NC];
    __shared__ float red_b1[4][BM];
    __shared__ float red_b2[4][BM];
    __shared__ int   red_i1[4][BM];
    __shared__ int   bif[BM];

    const int tid = threadIdx.x;
    const int m0 = blockIdx.x * BM;
    const int l = tid & 63, wid = tid >> 6;
    const int wc0 = wid * 64;            // wave col base within chunk
    const int g = l >> 4, c = l & 15;
    const int ar = tid >> 2, akq = tid & 3;   // A staging: row, k-quad(8 floats)

    // csq for all 512 codes (also warms L1/L2 with the codebook)
    #pragma unroll
    for (int cc = 0; cc < 2; ++cc) {
        const int code = tid + cc * 256;
        const float* p = Cb + (size_t)code * DD;
        float b0 = pw128_sq(p), b1 = pw128_sq(p + 128);
        float b2 = pw128_sq(p + 256), b3 = pw128_sq(p + 384);
        csq[code] = __fadd_rn(__fadd_rn(b0, b1), __fadd_rn(b2, b3));
    }

    float rb1 = FINF, rb2 = FINF; int ri1 = 0;   // running best (tid<64)

    // prologue: load+split tile 0 into buf 0; load va = tile 1; prime B ring
    float4 va0, va1;
    {
        const float* zp = Z + (size_t)(m0 + ar) * DD + akq * 8;
        va0 = *(const float4*)zp;
        va1 = *(const float4*)(zp + 4);
        uint2 h0, l0, h1, l1;
        split4(va0, &h0, &l0);
        split4(va1, &h1, &l1);
        *(uint4*)&Ahi[0][ar * ASTR + akq * 8] = make_uint4(h0.x, h0.y, h1.x, h1.y);
        *(uint4*)&Alo[0][ar * ASTR + akq * 8] = make_uint4(l0.x, l0.y, l1.x, l1.y);
        zp = Z + (size_t)(m0 + ar) * DD + BK + akq * 8;   // tile 1 (kt=32)
        va0 = *(const float4*)zp;
        va1 = *(const float4*)(zp + 4);
    }
    float4 ring[4];
    #pragma unroll
    for (int j = 0; j < 2; ++j) {
        int C = wc0 + j * 16 + c;
        ring[2 * j]     = *(const float4*)(Cb + (size_t)C * DD + g * 8);
        ring[2 * j + 1] = *(const float4*)(Cb + (size_t)C * DD + g * 8 + 4);
    }
    __syncthreads();

    f32x4 acc[4][4];
    int cur = 0;

    for (int step = 0; step < 32; ++step) {
        const int n0 = (step >> 4) * BN;
        const int t1 = (step < 31) ? step + 1 : 31;      // tile for ring refill
        const int ktn = (t1 & 15) * BK, n0n = (t1 >> 4) * BN;
        const int t2 = (step < 30) ? step + 2 : 31;      // tile for va reload
        const int kt2 = (t2 & 15) * BK;
        const int nxt = cur ^ 1;

        if ((step & 15) == 0) {
            #pragma unroll
            for (int i = 0; i < 4; ++i)
                #pragma unroll
                for (int j = 0; j < 4; ++j) acc[i][j] = (f32x4)0.0f;
        }

        // A fragments from buf[cur] (issue early; bf16 hi/lo direct)
        bf16x8 ah[4], al[4];
        #pragma unroll
        for (int i = 0; i < 4; ++i) {
            int R = i * 16 + c;
            ah[i] = *(bf16x8*)&Ahi[cur][R * ASTR + g * 8];
            al[i] = *(bf16x8*)&Alo[cur][R * ASTR + g * 8];
        }

        // split va (tile step+1) -> buf[nxt]; then reload va = tile step+2
        {
            uint2 h0, l0, h1, l1;
            split4(va0, &h0, &l0);
            split4(va1, &h1, &l1);
            *(uint4*)&Ahi[nxt][ar * ASTR + akq * 8] = make_uint4(h0.x, h0.y, h1.x, h1.y);
            *(uint4*)&Alo[nxt][ar * ASTR + akq * 8] = make_uint4(l0.x, l0.y, l1.x, l1.y);
            const float* zp = Z + (size_t)(m0 + ar) * DD + kt2 + akq * 8;
            va0 = *(const float4*)zp;
            va1 = *(const float4*)(zp + 4);
        }

        // B ring consume/refill + 48 MFMA (hi*hi + hi*lo + lo*hi)
        #pragma unroll
        for (int j = 0; j < 4; ++j) {
            bf16x8 bh, bl;
            cvt8(ring[2 * (j & 1)], ring[2 * (j & 1) + 1], &bh, &bl);
            {
                const int jj = (j < 2) ? (j + 2) : (j - 2);
                const int kk = (j < 2) ? ((step & 15) * BK) : ktn;
                const int nn = (j < 2) ? n0 : n0n;
                const int C = nn + wc0 + jj * 16 + c;
                ring[2 * (j & 1)]     = *(const float4*)(Cb + (size_t)C * DD + kk + g * 8);
                ring[2 * (j & 1) + 1] = *(const float4*)(Cb + (size_t)C * DD + kk + g * 8 + 4);
            }
            #pragma unroll
            for (int i = 0; i < 4; ++i) {
                acc[i][j] = __builtin_amdgcn_mfma_f32_16x16x32_bf16(ah[i], bh, acc[i][j], 0, 0, 0);
                acc[i][j] = __builtin_amdgcn_mfma_f32_16x16x32_bf16(ah[i], bl, acc[i][j], 0, 0, 0);
                acc[i][j] = __builtin_amdgcn_mfma_f32_16x16x32_bf16(al[i], bh, acc[i][j], 0, 0, 0);
            }
        }

        if ((step & 15) == 15) {
            // chunk epilogue: metric + per-row best/best2
            #pragma unroll
            for (int i = 0; i < 4; ++i) {
                #pragma unroll
                for (int r = 0; r < 4; ++r) {
                    float b1 = FINF, b2 = FINF; int i1 = 0;
                    #pragma unroll
                    for (int j = 0; j < 4; ++j) {
                        int code = n0 + wc0 + j * 16 + c;
                        float m = fmaf(-2.0f, acc[i][j][r], csq[code]);
                        if (m < b1) { b2 = b1; b1 = m; i1 = code; }
                        else b2 = fminf(b2, m);
                    }
                    #pragma unroll
                    for (int s = 1; s < 16; s <<= 1) {
                        float ob1 = __shfl_xor(b1, s);
                        float ob2 = __shfl_xor(b2, s);
                        int oi1 = __shfl_xor(i1, s);
                        if (ob1 < b1 || (ob1 == b1 && oi1 < i1)) {
                            b2 = fminf(b1, ob2); b1 = ob1; i1 = oi1;
                        } else {
                            b2 = fminf(b2, ob1);
                        }
                    }
                    if (c == 0) {
                        int row = i * 16 + g * 4 + r;
                        red_b1[wid][row] = b1;
                        red_b2[wid][row] = b2;
                        red_i1[wid][row] = i1;
                    }
                }
            }
            __syncthreads();
            if (tid < BM) {
                #pragma unroll
                for (int h = 0; h < 4; ++h) {   // ascending code order
                    float nb1 = red_b1[h][tid], nb2 = red_b2[h][tid];
                    int ni = red_i1[h][tid];
                    if (nb1 < rb1) { rb2 = fminf(rb1, nb2); rb1 = nb1; ri1 = ni; }
                    else rb2 = fminf(rb2, nb1);
                }
            }
        }

        __syncthreads();   // buf[nxt] writes visible; buf[cur] reads done (WAR)
        cur = nxt;
    }

    if (tid < BM) {
        bif[tid] = ri1;
        out[(size_t)BQ * NC + m0 + tid] = (float)ri1;
        if (rb2 - rb1 < MARGIN) {
            int slot = atomicAdd(wslist, 1);
            if (slot < cap) wslist[1 + slot] = m0 + tid;
        }
    }
    __syncthreads();

    // one_hot: 64 rows x 512 cols, coalesced float4 stores
    #pragma unroll 4
    for (int t = 0; t < 32; ++t) {
        int f4i = tid + t * 256;
        int r = f4i >> 7, c4 = f4i & 127;
        int tgt = bif[r];
        int base = c4 * 4;
        float4 v;
        v.x = (tgt == base + 0) ? 1.0f : 0.0f;
        v.y = (tgt == base + 1) ? 1.0f : 0.0f;
        v.z = (tgt == base + 2) ? 1.0f : 0.0f;
        v.w = (tgt == base + 3) ? 1.0f : 0.0f;
        *(float4*)(out + (size_t)(m0 + r) * NC + (size_t)base) = v;
    }
}

// Pass 2: fp64-exact argmin for marginal rows (matches numpy-fp64 argmin).
__global__ __launch_bounds__(256) void fixup_kernel(
    const float* __restrict__ Z, const float* __restrict__ Cb,
    float* __restrict__ out, const int* __restrict__ wslist, int cap) {

    __shared__ float zrow[DD];
    __shared__ double md[256];
    __shared__ int mi[256];
    const int tid = threadIdx.x;
    int count = wslist[0];
    if (count > cap) count = cap;

    for (int e = blockIdx.x; e < count; e += gridDim.x) {
        const int row = wslist[1 + e];
        zrow[tid] = Z[(size_t)row * DD + tid];
        zrow[tid + 256] = Z[(size_t)row * DD + 256 + tid];
        __syncthreads();

        double bb = 1e300; int bidx = 0;
        #pragma unroll
        for (int cc = 0; cc < 2; ++cc) {
            const int code = tid * 2 + cc;
            const float* cp = Cb + (size_t)code * DD;
            double dot = 0.0, cs = 0.0;
            for (int k = 0; k < DD; k += 4) {
                float4 c4 = *(const float4*)(cp + k);
                double a0 = (double)zrow[k + 0], c0 = (double)c4.x;
                double a1 = (double)zrow[k + 1], c1 = (double)c4.y;
                double a2 = (double)zrow[k + 2], c2 = (double)c4.z;
                double a3 = (double)zrow[k + 3], c3 = (double)c4.w;
                dot = fma(a0, c0, dot); cs = fma(c0, c0, cs);
                dot = fma(a1, c1, dot); cs = fma(c1, c1, cs);
                dot = fma(a2, c2, dot); cs = fma(c2, c2, cs);
                dot = fma(a3, c3, dot); cs = fma(c3, c3, cs);
            }
            double m = cs - 2.0 * dot;
            if (m < bb || (m == bb && code < bidx)) { bb = m; bidx = code; }
        }
        md[tid] = bb; mi[tid] = bidx;
        __syncthreads();
        for (int s = 128; s > 0; s >>= 1) {
            if (tid < s) {
                if (md[tid + s] < md[tid] ||
                    (md[tid + s] == md[tid] && mi[tid + s] < mi[tid])) {
                    md[tid] = md[tid + s]; mi[tid] = mi[tid + s];
                }
            }
            __syncthreads();
        }
        const int imin = mi[0];
        out[(size_t)row * NC + tid] = (tid == imin) ? 1.0f : 0.0f;
        out[(size_t)row * NC + 256 + tid] = (tid + 256 == imin) ? 1.0f : 0.0f;
        if (tid == 0) out[(size_t)BQ * NC + row] = (float)imin;
        __syncthreads();
    }
}

extern "C" void kernel_launch(void* const* d_in, const int* in_sizes, int n_in,
                              void* d_out, int out_size, void* d_ws, size_t ws_size,
                              hipStream_t stream) {
    const float* Z = (const float*)d_in[0];
    const float* Cb = (const float*)d_in[1];
    float* out = (float*)d_out;
    int* wslist = (int*)d_ws;
    int cap = (int)(ws_size / 4) - 1;
    if (cap > BQ) cap = BQ;
    hipMemsetAsync(d_ws, 0, 4, stream);
    codebook_kernel<<<dim3(BQ / BM), dim3(256), 0, stream>>>(Z, Cb, out, wslist, cap);
    fixup_kernel<<<dim3(512), dim3(256), 0, stream>>>(Z, Cb, out, wslist, cap);
}

// Round 9
// 286.570 us; speedup vs baseline: 1.5184x; 1.5184x over previous
//
#include <hip/hip_runtime.h>
#include <math.h>

#define BQ 65536
#define NC 512
#define DD 512
#define BM 64
#define BN 256
#define BK 32
#define MARGIN 3e-3f
#define FINF 3.402823466e38f

// A-tile LDS rows padded to 40 shorts (80 B).
#define ASTR 40

typedef short bf16x8 __attribute__((ext_vector_type(8)));
typedef float f32x4 __attribute__((ext_vector_type(4)));

__device__ __forceinline__ unsigned int cvt_pk_bf16(float a, float b) {
    unsigned int r;
    asm("v_cvt_pk_bf16_f32 %0, %1, %2" : "=v"(r) : "v"(a), "v"(b));
    return r;  // low16 = bf16(a) RNE, high16 = bf16(b)
}

// Split 4 fp32 into packed bf16 hi-pairs and lo-pairs (verified since r3).
__device__ __forceinline__ void split4(float4 v, uint2* hi, uint2* lo) {
    unsigned int h0 = cvt_pk_bf16(v.x, v.y);
    unsigned int h1 = cvt_pk_bf16(v.z, v.w);
    float hx = __uint_as_float(h0 << 16);
    float hy = __uint_as_float(h0 & 0xFFFF0000u);
    float hz = __uint_as_float(h1 << 16);
    float hw = __uint_as_float(h1 & 0xFFFF0000u);
    *hi = make_uint2(h0, h1);
    *lo = make_uint2(cvt_pk_bf16(v.x - hx, v.y - hy),
                     cvt_pk_bf16(v.z - hz, v.w - hw));
}

// 8 fp32 -> bf16 hi + lo vectors (same arithmetic as split4).
__device__ __forceinline__ void cvt8(float4 f0, float4 f1,
                                     bf16x8* hi, bf16x8* lo) {
    unsigned int h01 = cvt_pk_bf16(f0.x, f0.y);
    unsigned int h23 = cvt_pk_bf16(f0.z, f0.w);
    unsigned int h45 = cvt_pk_bf16(f1.x, f1.y);
    unsigned int h67 = cvt_pk_bf16(f1.z, f1.w);
    float a0 = __uint_as_float(h01 << 16), a1 = __uint_as_float(h01 & 0xFFFF0000u);
    float a2 = __uint_as_float(h23 << 16), a3 = __uint_as_float(h23 & 0xFFFF0000u);
    float a4 = __uint_as_float(h45 << 16), a5 = __uint_as_float(h45 & 0xFFFF0000u);
    float a6 = __uint_as_float(h67 << 16), a7 = __uint_as_float(h67 & 0xFFFF0000u);
    union { bf16x8 v; unsigned int u[4]; } H, L;
    H.u[0] = h01; H.u[1] = h23; H.u[2] = h45; H.u[3] = h67;
    L.u[0] = cvt_pk_bf16(f0.x - a0, f0.y - a1);
    L.u[1] = cvt_pk_bf16(f0.z - a2, f0.w - a3);
    L.u[2] = cvt_pk_bf16(f1.x - a4, f1.y - a5);
    L.u[3] = cvt_pk_bf16(f1.z - a6, f1.w - a7);
    *hi = H.v; *lo = L.v;
}

__device__ __forceinline__ float pw128_sq(const float* __restrict__ p) {
    float r[8];
    #pragma unroll
    for (int j = 0; j < 8; ++j) r[j] = 0.0f;
    #pragma unroll
    for (int q = 0; q < 32; ++q) {
        float4 v = *(const float4*)(p + q * 4);
        const int e = (q & 1) << 2;
        r[e + 0] = __fadd_rn(r[e + 0], __fmul_rn(v.x, v.x));
        r[e + 1] = __fadd_rn(r[e + 1], __fmul_rn(v.y, v.y));
        r[e + 2] = __fadd_rn(r[e + 2], __fmul_rn(v.z, v.z));
        r[e + 3] = __fadd_rn(r[e + 3], __fmul_rn(v.w, v.w));
    }
    return __fadd_rn(__fadd_rn(__fadd_rn(r[0], r[1]), __fadd_rn(r[2], r[3])),
                     __fadd_rn(__fadd_rn(r[4], r[5]), __fadd_rn(r[6], r[7])));
}

// Pass 0: csq once for the whole device (was recomputed by all 1024 blocks).
__global__ __launch_bounds__(256) void csq_kernel(const float* __restrict__ Cb,
                                                  float* __restrict__ csqg) {
    const int code = blockIdx.x * 256 + threadIdx.x;
    const float* p = Cb + (size_t)code * DD;
    float b0 = pw128_sq(p), b1 = pw128_sq(p + 128);
    float b2 = pw128_sq(p + 256), b3 = pw128_sq(p + 384);
    csqg[code] = __fadd_rn(__fadd_rn(b0, b1), __fadd_rn(b2, b3));
}

// Pass 1: BM=64, 4 waves x (64x64) tiles. A double-buffered in LDS as split
// bf16 (ONE barrier/step); B global->reg ring (static indices). Metric
// m = csq - 2 z.c, best+second-best; marginal rows -> fp64 fixup worklist.
// launch_bounds(256,3): 170-reg unified budget (64 acc + ~106 arch) -> the
// r8 spills (VGPR_Count 64, +190MB scratch) are gone at 3 waves/SIMD.
__global__ __launch_bounds__(256, 3) void codebook_kernel(
    const float* __restrict__ Z, const float* __restrict__ Cb,
    const float* __restrict__ csqg,
    float* __restrict__ out, int* __restrict__ wslist, int cap) {

    __shared__ __align__(16) unsigned short Ahi[2][BM * ASTR];
    __shared__ __align__(16) unsigned short Alo[2][BM * ASTR];
    __shared__ float csq[NC];
    __shared__ float red_b1[4][BM];
    __shared__ float red_b2[4][BM];
    __shared__ int   red_i1[4][BM];
    __shared__ int   bif[BM];

    const int tid = threadIdx.x;
    const int m0 = blockIdx.x * BM;
    const int l = tid & 63, wid = tid >> 6;
    const int wc0 = wid * 64;            // wave col base within chunk
    const int g = l >> 4, c = l & 15;
    const int ar = tid >> 2, akq = tid & 3;   // A staging: row, k-quad(8 floats)

    // csq from precomputed global (bit-identical values to r8's in-block calc)
    if (tid < 128) {
        *(float4*)&csq[tid * 4] = *(const float4*)(csqg + tid * 4);
    }

    float rb1 = FINF, rb2 = FINF; int ri1 = 0;   // running best (tid<64)

    // prologue: load+split tile 0 into buf 0; load va = tile 1; prime B ring
    float4 va0, va1;
    {
        const float* zp = Z + (size_t)(m0 + ar) * DD + akq * 8;
        va0 = *(const float4*)zp;
        va1 = *(const float4*)(zp + 4);
        uint2 h0, l0, h1, l1;
        split4(va0, &h0, &l0);
        split4(va1, &h1, &l1);
        *(uint4*)&Ahi[0][ar * ASTR + akq * 8] = make_uint4(h0.x, h0.y, h1.x, h1.y);
        *(uint4*)&Alo[0][ar * ASTR + akq * 8] = make_uint4(l0.x, l0.y, l1.x, l1.y);
        zp = Z + (size_t)(m0 + ar) * DD + BK + akq * 8;   // tile 1 (kt=32)
        va0 = *(const float4*)zp;
        va1 = *(const float4*)(zp + 4);
    }
    float4 ring[4];
    #pragma unroll
    for (int j = 0; j < 2; ++j) {
        int C = wc0 + j * 16 + c;
        ring[2 * j]     = *(const float4*)(Cb + (size_t)C * DD + g * 8);
        ring[2 * j + 1] = *(const float4*)(Cb + (size_t)C * DD + g * 8 + 4);
    }
    __syncthreads();

    f32x4 acc[4][4];
    int cur = 0;

    for (int step = 0; step < 32; ++step) {
        const int n0 = (step >> 4) * BN;
        const int t1 = (step < 31) ? step + 1 : 31;      // tile for ring refill
        const int ktn = (t1 & 15) * BK, n0n = (t1 >> 4) * BN;
        const int t2 = (step < 30) ? step + 2 : 31;      // tile for va reload
        const int kt2 = (t2 & 15) * BK;
        const int nxt = cur ^ 1;

        if ((step & 15) == 0) {
            #pragma unroll
            for (int i = 0; i < 4; ++i)
                #pragma unroll
                for (int j = 0; j < 4; ++j) acc[i][j] = (f32x4)0.0f;
        }

        // A fragments from buf[cur] (issue early; bf16 hi/lo direct)
        bf16x8 ah[4], al[4];
        #pragma unroll
        for (int i = 0; i < 4; ++i) {
            int R = i * 16 + c;
            ah[i] = *(bf16x8*)&Ahi[cur][R * ASTR + g * 8];
            al[i] = *(bf16x8*)&Alo[cur][R * ASTR + g * 8];
        }

        // split va (tile step+1) -> buf[nxt]; then reload va = tile step+2
        {
            uint2 h0, l0, h1, l1;
            split4(va0, &h0, &l0);
            split4(va1, &h1, &l1);
            *(uint4*)&Ahi[nxt][ar * ASTR + akq * 8] = make_uint4(h0.x, h0.y, h1.x, h1.y);
            *(uint4*)&Alo[nxt][ar * ASTR + akq * 8] = make_uint4(l0.x, l0.y, l1.x, l1.y);
            const float* zp = Z + (size_t)(m0 + ar) * DD + kt2 + akq * 8;
            va0 = *(const float4*)zp;
            va1 = *(const float4*)(zp + 4);
        }

        // B ring consume/refill + 48 MFMA (hi*hi + hi*lo + lo*hi)
        #pragma unroll
        for (int j = 0; j < 4; ++j) {
            bf16x8 bh, bl;
            cvt8(ring[2 * (j & 1)], ring[2 * (j & 1) + 1], &bh, &bl);
            {
                const int jj = (j < 2) ? (j + 2) : (j - 2);
                const int kk = (j < 2) ? ((step & 15) * BK) : ktn;
                const int nn = (j < 2) ? n0 : n0n;
                const int C = nn + wc0 + jj * 16 + c;
                ring[2 * (j & 1)]     = *(const float4*)(Cb + (size_t)C * DD + kk + g * 8);
                ring[2 * (j & 1) + 1] = *(const float4*)(Cb + (size_t)C * DD + kk + g * 8 + 4);
            }
            #pragma unroll
            for (int i = 0; i < 4; ++i) {
                acc[i][j] = __builtin_amdgcn_mfma_f32_16x16x32_bf16(ah[i], bh, acc[i][j], 0, 0, 0);
                acc[i][j] = __builtin_amdgcn_mfma_f32_16x16x32_bf16(ah[i], bl, acc[i][j], 0, 0, 0);
                acc[i][j] = __builtin_amdgcn_mfma_f32_16x16x32_bf16(al[i], bh, acc[i][j], 0, 0, 0);
            }
        }

        if ((step & 15) == 15) {
            // chunk epilogue: metric + per-row best/best2
            #pragma unroll
            for (int i = 0; i < 4; ++i) {
                #pragma unroll
                for (int r = 0; r < 4; ++r) {
                    float b1 = FINF, b2 = FINF; int i1 = 0;
                    #pragma unroll
                    for (int j = 0; j < 4; ++j) {
                        int code = n0 + wc0 + j * 16 + c;
                        float m = fmaf(-2.0f, acc[i][j][r], csq[code]);
                        if (m < b1) { b2 = b1; b1 = m; i1 = code; }
                        else b2 = fminf(b2, m);
                    }
                    #pragma unroll
                    for (int s = 1; s < 16; s <<= 1) {
                        float ob1 = __shfl_xor(b1, s);
                        float ob2 = __shfl_xor(b2, s);
                        int oi1 = __shfl_xor(i1, s);
                        if (ob1 < b1 || (ob1 == b1 && oi1 < i1)) {
                            b2 = fminf(b1, ob2); b1 = ob1; i1 = oi1;
                        } else {
                            b2 = fminf(b2, ob1);
                        }
                    }
                    if (c == 0) {
                        int row = i * 16 + g * 4 + r;
                        red_b1[wid][row] = b1;
                        red_b2[wid][row] = b2;
                        red_i1[wid][row] = i1;
                    }
                }
            }
            __syncthreads();
            if (tid < BM) {
                #pragma unroll
                for (int h = 0; h < 4; ++h) {   // ascending code order
                    float nb1 = red_b1[h][tid], nb2 = red_b2[h][tid];
                    int ni = red_i1[h][tid];
                    if (nb1 < rb1) { rb2 = fminf(rb1, nb2); rb1 = nb1; ri1 = ni; }
                    else rb2 = fminf(rb2, nb1);
                }
            }
        }

        __syncthreads();   // buf[nxt] writes visible; buf[cur] reads done (WAR)
        cur = nxt;
    }

    if (tid < BM) {
        bif[tid] = ri1;
        out[(size_t)BQ * NC + m0 + tid] = (float)ri1;
        if (rb2 - rb1 < MARGIN) {
            int slot = atomicAdd(wslist, 1);
            if (slot < cap) wslist[1 + slot] = m0 + tid;
        }
    }
    __syncthreads();

    // one_hot: 64 rows x 512 cols, coalesced float4 stores
    #pragma unroll 4
    for (int t = 0; t < 32; ++t) {
        int f4i = tid + t * 256;
        int r = f4i >> 7, c4 = f4i & 127;
        int tgt = bif[r];
        int base = c4 * 4;
        float4 v;
        v.x = (tgt == base + 0) ? 1.0f : 0.0f;
        v.y = (tgt == base + 1) ? 1.0f : 0.0f;
        v.z = (tgt == base + 2) ? 1.0f : 0.0f;
        v.w = (tgt == base + 3) ? 1.0f : 0.0f;
        *(float4*)(out + (size_t)(m0 + r) * NC + (size_t)base) = v;
    }
}

// Pass 2: fp64-exact argmin for marginal rows (matches numpy-fp64 argmin).
__global__ __launch_bounds__(256) void fixup_kernel(
    const float* __restrict__ Z, const float* __restrict__ Cb,
    float* __restrict__ out, const int* __restrict__ wslist, int cap) {

    __shared__ float zrow[DD];
    __shared__ double md[256];
    __shared__ int mi[256];
    const int tid = threadIdx.x;
    int count = wslist[0];
    if (count > cap) count = cap;

    for (int e = blockIdx.x; e < count; e += gridDim.x) {
        const int row = wslist[1 + e];
        zrow[tid] = Z[(size_t)row * DD + tid];
        zrow[tid + 256] = Z[(size_t)row * DD + 256 + tid];
        __syncthreads();

        double bb = 1e300; int bidx = 0;
        #pragma unroll
        for (int cc = 0; cc < 2; ++cc) {
            const int code = tid * 2 + cc;
            const float* cp = Cb + (size_t)code * DD;
            double dot = 0.0, cs = 0.0;
            for (int k = 0; k < DD; k += 4) {
                float4 c4 = *(const float4*)(cp + k);
                double a0 = (double)zrow[k + 0], c0 = (double)c4.x;
                double a1 = (double)zrow[k + 1], c1 = (double)c4.y;
                double a2 = (double)zrow[k + 2], c2 = (double)c4.z;
                double a3 = (double)zrow[k + 3], c3 = (double)c4.w;
                dot = fma(a0, c0, dot); cs = fma(c0, c0, cs);
                dot = fma(a1, c1, dot); cs = fma(c1, c1, cs);
                dot = fma(a2, c2, dot); cs = fma(c2, c2, cs);
                dot = fma(a3, c3, dot); cs = fma(c3, c3, cs);
            }
            double m = cs - 2.0 * dot;
            if (m < bb || (m == bb && code < bidx)) { bb = m; bidx = code; }
        }
        md[tid] = bb; mi[tid] = bidx;
        __syncthreads();
        for (int s = 128; s > 0; s >>= 1) {
            if (tid < s) {
                if (md[tid + s] < md[tid] ||
                    (md[tid + s] == md[tid] && mi[tid + s] < mi[tid])) {
                    md[tid] = md[tid + s]; mi[tid] = mi[tid + s];
                }
            }
            __syncthreads();
        }
        const int imin = mi[0];
        out[(size_t)row * NC + tid] = (tid == imin) ? 1.0f : 0.0f;
        out[(size_t)row * NC + 256 + tid] = (tid + 256 == imin) ? 1.0f : 0.0f;
        if (tid == 0) out[(size_t)BQ * NC + row] = (float)imin;
        __syncthreads();
    }
}

extern "C" void kernel_launch(void* const* d_in, const int* in_sizes, int n_in,
                              void* d_out, int out_size, void* d_ws, size_t ws_size,
                              hipStream_t stream) {
    const float* Z = (const float*)d_in[0];
    const float* Cb = (const float*)d_in[1];
    float* out = (float*)d_out;
    float* csqg = (float*)d_ws;                  // [512] floats
    int* wslist = (int*)d_ws + NC;               // counter + worklist
    int cap = (int)(ws_size / 4) - NC - 1;
    if (cap > BQ) cap = BQ;
    csq_kernel<<<dim3(2), dim3(256), 0, stream>>>(Cb, csqg);
    hipMemsetAsync((char*)d_ws + NC * 4, 0, 4, stream);  // zero worklist counter
    codebook_kernel<<<dim3(BQ / BM), dim3(256), 0, stream>>>(Z, Cb, csqg, out, wslist, cap);
    fixup_kernel<<<dim3(512), dim3(256), 0, stream>>>(Z, Cb, out, wslist, cap);
}